// Round 1
// baseline (2372.001 us; speedup 1.0000x reference)
//
#include <hip/hip_runtime.h>

// ---- problem constants ----
#define BT      32768     // B*T = 128*256
#define T_SEQ   256
#define E_DIM   384
#define NH      6
#define NL      6
#define VOC     65
#define FF_DIM  1536
#define QKV_N   1152      // 3*E

typedef short bf16x8 __attribute__((ext_vector_type(8)));   // 8 bf16 (4 VGPRs), per guide
typedef float f32x4  __attribute__((ext_vector_type(4)));
typedef unsigned short u16;

typedef const unsigned int __attribute__((address_space(1))) gu32;
typedef unsigned int       __attribute__((address_space(3))) lu32;

__device__ __forceinline__ u16 f2bf(float x) {              // RNE fp32->bf16
  unsigned u = __builtin_bit_cast(unsigned, x);
  u += 0x7fffu + ((u >> 16) & 1u);
  return (u16)(u >> 16);
}

__device__ __forceinline__ void load_lds_16(const void* g, void* l) {
  // async global->LDS, 16B/lane, dest = wave-uniform base + lane*16
  __builtin_amdgcn_global_load_lds((gu32*)g, (lu32*)l, 16, 0, 0);
}

// ---------------- weight repack ----------------
// Wq/Wk/Wv [L][H][E][DH] fp32 -> rows (rowoff + h*64+d) of Wqkv_t [L][1152][384] bf16 (B^T layout)
__global__ __launch_bounds__(256) void repack_qkv(const float* __restrict__ src,
                                                  u16* __restrict__ dst, int rowoff) {
  int i = blockIdx.x * 256 + threadIdx.x;        // over L*H*E*DH = 884736
  int d  = i & 63;
  int e  = (i >> 6) % E_DIM;
  int hh = ((i >> 6) / E_DIM) % NH;
  int l  = i / (64 * E_DIM * NH);
  dst[((size_t)l * QKV_N + rowoff + hh * 64 + d) * E_DIM + e] = f2bf(src[i]);
}

// src [L][R][C] fp32 -> dst [L][C][R] bf16 (B^T layout)
__global__ __launch_bounds__(256) void transpose_b(const float* __restrict__ src,
                                                   u16* __restrict__ dst, int R, int C) {
  int l = blockIdx.y;
  long i = (long)blockIdx.x * 256 + threadIdx.x;
  if (i >= (long)R * C) return;
  int c = (int)(i % C), r = (int)(i / C);
  dst[((size_t)l * C + c) * (size_t)R + r] = f2bf(src[(size_t)l * R * C + i]);
}

// ---------------- embedding ----------------
__global__ __launch_bounds__(256) void embed_k(const int* __restrict__ idx,
                                               const float* __restrict__ tok,
                                               const float* __restrict__ pos,
                                               float* __restrict__ x) {
  int i = blockIdx.x * 256 + threadIdx.x;        // over BT*96 float4s
  int bt = i / 96, q = i - bt * 96;
  int t = bt & 255;
  float4 a = ((const float4*)tok)[(size_t)idx[bt] * 96 + q];
  float4 p = ((const float4*)pos)[(size_t)t * 96 + q];
  ((float4*)x)[i] = make_float4(a.x + p.x, a.y + p.y, a.z + p.z, a.w + p.w);
}

// ---------------- layernorm (fp32 in -> bf16 out) ----------------
__global__ __launch_bounds__(256) void ln_k(const float* __restrict__ x,
                                            const float* __restrict__ gam,
                                            const float* __restrict__ bet,
                                            u16* __restrict__ out) {
  int tid = threadIdx.x, lane = tid & 63, w = tid >> 6;
  size_t token = (size_t)blockIdx.x * 4 + w;
  const float* xr = x + token * E_DIM;
  float v[6]; float s = 0.f;
#pragma unroll
  for (int i = 0; i < 6; i++) { v[i] = xr[i * 64 + lane]; s += v[i]; }
#pragma unroll
  for (int d = 1; d < 64; d <<= 1) s += __shfl_xor(s, d);
  float mean = s * (1.f / E_DIM);
  float q = 0.f;
#pragma unroll
  for (int i = 0; i < 6; i++) { float d0 = v[i] - mean; q += d0 * d0; }
#pragma unroll
  for (int d = 1; d < 64; d <<= 1) q += __shfl_xor(q, d);
  float r = rsqrtf(q * (1.f / E_DIM) + 1e-5f);
#pragma unroll
  for (int i = 0; i < 6; i++) {
    int e = i * 64 + lane;
    out[token * E_DIM + e] = f2bf((v[i] - mean) * r * gam[e] + bet[e]);
  }
}

// ---------------- MFMA GEMM: C[M][N] = A[M][K](bf16) @ Bt[N][K](bf16)^T ----------------
// 128x128 tile, BK=32, 4 waves in 2x2, 4x4 16x16x32 MFMA per wave. m97 structure.
__global__ __launch_bounds__(256) void gemm_bt(
    const u16* __restrict__ A, const u16* __restrict__ Bt, int K, int Nstore,
    const float* __restrict__ bias, const float* __restrict__ resid,
    float* __restrict__ outF, u16* __restrict__ outH, int relu) {
  __shared__ u16 As[128 * 32];
  __shared__ u16 Bs[128 * 32];
  const int tid = threadIdx.x, lane = tid & 63, wv = tid >> 6;
  const int quad = lane >> 4, l16 = lane & 15;
  const int m0 = blockIdx.x * 128, n0 = blockIdx.y * 128;
  const int wm = (wv & 1) * 64, wn = (wv >> 1) * 64;
  const int srow = lane >> 2, scol = (lane & 3) * 8;

  f32x4 acc[4][4];
#pragma unroll
  for (int i = 0; i < 4; i++)
#pragma unroll
    for (int j = 0; j < 4; j++) acc[i][j] = (f32x4){0.f, 0.f, 0.f, 0.f};

  for (int k0 = 0; k0 < K; k0 += 32) {
    __syncthreads();                       // WAR: prior reads drained before overwrite
#pragma unroll
    for (int j = 0; j < 2; j++) {
      int rid = wv * 2 + j;
      int r = rid * 16 + srow;
      load_lds_16(A  + (size_t)(m0 + r) * K + (k0 + scol), &As[rid * 512]);
      load_lds_16(Bt + (size_t)(n0 + r) * K + (k0 + scol), &Bs[rid * 512]);
    }
    __syncthreads();                       // RAW: staging complete
    bf16x8 af[4], bfr[4];
#pragma unroll
    for (int i = 0; i < 4; i++) af[i]  = *(const bf16x8*)&As[(wm + i * 16 + l16) * 32 + quad * 8];
#pragma unroll
    for (int j = 0; j < 4; j++) bfr[j] = *(const bf16x8*)&Bs[(wn + j * 16 + l16) * 32 + quad * 8];
#pragma unroll
    for (int i = 0; i < 4; i++)
#pragma unroll
      for (int j = 0; j < 4; j++)
        acc[i][j] = __builtin_amdgcn_mfma_f32_16x16x32_bf16(af[i], bfr[j], acc[i][j], 0, 0, 0);
  }

  // epilogue: C/D layout row = quad*4+reg, col = lane&15
#pragma unroll
  for (int j = 0; j < 4; j++) {
    const int gn = n0 + wn + j * 16 + l16;
    if (gn < Nstore) {
      const float bv = bias ? bias[gn] : 0.f;
#pragma unroll
      for (int i = 0; i < 4; i++) {
#pragma unroll
        for (int r = 0; r < 4; r++) {
          const int gm = m0 + wm + i * 16 + quad * 4 + r;
          float v = acc[i][j][r] + bv;
          if (relu) v = fmaxf(v, 0.f);
          const size_t o = (size_t)gm * Nstore + gn;
          if (outF) outF[o] = v + (resid ? resid[o] : 0.f);
          else      outH[o] = f2bf(v);
        }
      }
    }
  }
}

// ---------------- fused causal attention ----------------
// one block per (b,h); 8 waves x 32 q-rows; s-chunks of 64 staged in LDS; online softmax.
__global__ __launch_bounds__(512) void attn_k(const u16* __restrict__ qkv,
                                              u16* __restrict__ att) {
  __shared__ u16 Kc[64 * 64];      // K chunk  [s][d]   (B^T storage for QK^T)
  __shared__ u16 Vtc[64 * 64];     // V^T chunk [d][s]  (B^T storage for P@V)
  __shared__ u16 Pl[8 * 32 * 64];  // per-wave P buffer (C-layout -> A-layout round-trip)
  const int b = blockIdx.x / NH, h = blockIdx.x % NH;
  const int tid = threadIdx.x, lane = tid & 63, w = tid >> 6;
  const int quad = lane >> 4, l16 = lane & 15;
  const int rowb = b * T_SEQ;

  // Q fragments (A-layout) straight from global, resident all kernel
  bf16x8 qf[2][2];
#pragma unroll
  for (int mi = 0; mi < 2; mi++)
#pragma unroll
    for (int kk = 0; kk < 2; kk++)
      qf[mi][kk] = *(const bf16x8*)(qkv + (size_t)(rowb + w * 32 + mi * 16 + l16) * QKV_N +
                                    h * 64 + kk * 32 + quad * 8);

  f32x4 Oa[2][4];
  float mrun[2][4], lrun[2][4];
#pragma unroll
  for (int mi = 0; mi < 2; mi++) {
#pragma unroll
    for (int di = 0; di < 4; di++) Oa[mi][di] = (f32x4){0.f, 0.f, 0.f, 0.f};
#pragma unroll
    for (int r = 0; r < 4; r++) { mrun[mi][r] = -1e30f; lrun[mi][r] = 0.f; }
  }

  u16* Pw = &Pl[w * 2048];
  const int nch = (w >> 1) + 1;            // causal: wave w needs chunks 0..w/2
  const int sr = tid >> 3, sseg = (tid & 7) * 8;

  for (int c = 0; c < 4; c++) {
    const int s0 = c * 64;
    __syncthreads();
    // stage K chunk (coalesced 16B)
    *(uint4*)&Kc[sr * 64 + sseg] =
        *(const uint4*)(qkv + (size_t)(rowb + s0 + sr) * QKV_N + 384 + h * 64 + sseg);
    // stage V^T chunk (vector read, scalar LDS scatter)
    {
      union { uint4 u; u16 us[8]; } tb;
      tb.u = *(const uint4*)(qkv + (size_t)(rowb + s0 + sr) * QKV_N + 768 + h * 64 + sseg);
#pragma unroll
      for (int j = 0; j < 8; j++) Vtc[(sseg + j) * 64 + sr] = tb.us[j];
    }
    __syncthreads();
    if (c >= nch) continue;                // barrier counts still match across waves

    // S = Q @ K^T
    f32x4 S[2][4];
    bf16x8 kf[4][2];
#pragma unroll
    for (int ni = 0; ni < 4; ni++)
#pragma unroll
      for (int kk = 0; kk < 2; kk++)
        kf[ni][kk] = *(const bf16x8*)&Kc[(ni * 16 + l16) * 64 + kk * 32 + quad * 8];
#pragma unroll
    for (int mi = 0; mi < 2; mi++)
#pragma unroll
      for (int ni = 0; ni < 4; ni++) {
        f32x4 z = (f32x4){0.f, 0.f, 0.f, 0.f};
        z = __builtin_amdgcn_mfma_f32_16x16x32_bf16(qf[mi][0], kf[ni][0], z, 0, 0, 0);
        S[mi][ni] = __builtin_amdgcn_mfma_f32_16x16x32_bf16(qf[mi][1], kf[ni][1], z, 0, 0, 0);
      }
    const bool diag = (c == nch - 1);
#pragma unroll
    for (int mi = 0; mi < 2; mi++)
#pragma unroll
      for (int ni = 0; ni < 4; ni++)
#pragma unroll
        for (int r = 0; r < 4; r++) {
          float xv = S[mi][ni][r] * 0.125f;          // DH^-0.5
          if (diag) {
            int t = w * 32 + mi * 16 + quad * 4 + r;
            int s = s0 + ni * 16 + l16;
            if (s > t) xv = -1e30f;
          }
          S[mi][ni][r] = xv;
        }
    // online softmax; row lives in 16 lanes of one quad (xor 1,2,4,8)
#pragma unroll
    for (int mi = 0; mi < 2; mi++)
#pragma unroll
      for (int r = 0; r < 4; r++) {
        float mx = fmaxf(fmaxf(S[mi][0][r], S[mi][1][r]), fmaxf(S[mi][2][r], S[mi][3][r]));
        mx = fmaxf(mx, __shfl_xor(mx, 1));
        mx = fmaxf(mx, __shfl_xor(mx, 2));
        mx = fmaxf(mx, __shfl_xor(mx, 4));
        mx = fmaxf(mx, __shfl_xor(mx, 8));
        float mnew = fmaxf(mrun[mi][r], mx);
        float alpha = __expf(mrun[mi][r] - mnew);
        float ls = 0.f;
#pragma unroll
        for (int ni = 0; ni < 4; ni++) {
          float p = __expf(S[mi][ni][r] - mnew);
          S[mi][ni][r] = p; ls += p;
        }
        ls += __shfl_xor(ls, 1); ls += __shfl_xor(ls, 2);
        ls += __shfl_xor(ls, 4); ls += __shfl_xor(ls, 8);
        lrun[mi][r] = lrun[mi][r] * alpha + ls;
        mrun[mi][r] = mnew;
#pragma unroll
        for (int di = 0; di < 4; di++) Oa[mi][di][r] *= alpha;
      }
    // P: C-layout regs -> LDS (A-layout readable)
#pragma unroll
    for (int mi = 0; mi < 2; mi++)
#pragma unroll
      for (int ni = 0; ni < 4; ni++)
#pragma unroll
        for (int r = 0; r < 4; r++)
          Pw[(mi * 16 + quad * 4 + r) * 64 + ni * 16 + l16] = f2bf(S[mi][ni][r]);
    // O += P @ V
    bf16x8 pf[2][2], vf[4][2];
#pragma unroll
    for (int mi = 0; mi < 2; mi++)
#pragma unroll
      for (int kk = 0; kk < 2; kk++)
        pf[mi][kk] = *(const bf16x8*)&Pw[(mi * 16 + l16) * 64 + kk * 32 + quad * 8];
#pragma unroll
    for (int di = 0; di < 4; di++)
#pragma unroll
      for (int kk = 0; kk < 2; kk++)
        vf[di][kk] = *(const bf16x8*)&Vtc[(di * 16 + l16) * 64 + kk * 32 + quad * 8];
#pragma unroll
    for (int mi = 0; mi < 2; mi++)
#pragma unroll
      for (int di = 0; di < 4; di++) {
        Oa[mi][di] = __builtin_amdgcn_mfma_f32_16x16x32_bf16(pf[mi][0], vf[di][0], Oa[mi][di], 0, 0, 0);
        Oa[mi][di] = __builtin_amdgcn_mfma_f32_16x16x32_bf16(pf[mi][1], vf[di][1], Oa[mi][di], 0, 0, 0);
      }
  }

  // normalize + store att[b,t, h*64+d] bf16
#pragma unroll
  for (int mi = 0; mi < 2; mi++)
#pragma unroll
    for (int r = 0; r < 4; r++) {
      float inv = 1.f / lrun[mi][r];
      int t = w * 32 + mi * 16 + quad * 4 + r;
#pragma unroll
      for (int di = 0; di < 4; di++)
        att[(size_t)(rowb + t) * E_DIM + h * 64 + di * 16 + l16] = f2bf(Oa[mi][di][r] * inv);
    }
}

// ---------------- loss ----------------
__global__ __launch_bounds__(256) void loss_k(const float* __restrict__ logits,
                                              const int* __restrict__ tgt,
                                              float* __restrict__ loss) {
  __shared__ float part[4];
  int tid = threadIdx.x, lane = tid & 63, w = tid >> 6;
  size_t t = (size_t)blockIdx.x * 4 + w;
  const float* row = logits + t * VOC;
  float a = row[lane];
  float b = (lane == 0) ? row[64] : -1e30f;
  float mx = fmaxf(a, b);
#pragma unroll
  for (int d = 1; d < 64; d <<= 1) mx = fmaxf(mx, __shfl_xor(mx, d));
  float sum = __expf(a - mx) + ((lane == 0) ? __expf(b - mx) : 0.f);
#pragma unroll
  for (int d = 1; d < 64; d <<= 1) sum += __shfl_xor(sum, d);
  if (lane == 0) {
    float lse = mx + __logf(sum);
    part[w] = lse - row[tgt[t]];
  }
  __syncthreads();
  if (tid == 0)
    atomicAdd(loss, (part[0] + part[1] + part[2] + part[3]) * (1.f / (float)BT));
}

// ---------------- host ----------------
extern "C" void kernel_launch(void* const* d_in, const int* in_sizes, int n_in,
                              void* d_out, int out_size, void* d_ws, size_t ws_size,
                              hipStream_t stream) {
  (void)in_sizes; (void)n_in; (void)out_size; (void)ws_size;
  const int*   idx  = (const int*)d_in[0];
  const int*   tgt  = (const int*)d_in[1];
  const float* tok  = (const float*)d_in[2];
  const float* pos  = (const float*)d_in[3];
  const float* Wq   = (const float*)d_in[4];
  const float* Wk   = (const float*)d_in[5];
  const float* Wv   = (const float*)d_in[6];
  const float* Wo   = (const float*)d_in[7];
  const float* bo   = (const float*)d_in[8];
  const float* ln1s = (const float*)d_in[9];
  const float* ln1b = (const float*)d_in[10];
  const float* ln2s = (const float*)d_in[11];
  const float* ln2b = (const float*)d_in[12];
  const float* W1   = (const float*)d_in[13];
  const float* b1   = (const float*)d_in[14];
  const float* W2   = (const float*)d_in[15];
  const float* b2   = (const float*)d_in[16];
  const float* lnfs = (const float*)d_in[17];
  const float* lnfb = (const float*)d_in[18];
  const float* Wout = (const float*)d_in[19];
  const float* bout = (const float*)d_in[20];

  char* w = (char*)d_ws;
  float* x    = (float*)w;  w += (size_t)BT * E_DIM * 4;
  u16* hb     = (u16*)w;    w += (size_t)BT * E_DIM * 2;
  u16* attb   = (u16*)w;    w += (size_t)BT * E_DIM * 2;
  u16* big    = (u16*)w;    w += (size_t)BT * FF_DIM * 2;     // qkv / ff union
  u16* Wqkv_t = (u16*)w;    w += (size_t)NL * QKV_N * E_DIM * 2;
  u16* Wo_t   = (u16*)w;    w += (size_t)NL * E_DIM * E_DIM * 2;
  u16* W1_t   = (u16*)w;    w += (size_t)NL * FF_DIM * E_DIM * 2;
  u16* W2_t   = (u16*)w;    w += (size_t)NL * E_DIM * FF_DIM * 2;
  u16* Wout_t = (u16*)w;    w += (size_t)128 * E_DIM * 2;
  u16* qkv = big;
  u16* ff  = big;

  float* logits = (float*)d_out;
  float* loss   = logits + (size_t)BT * VOC;

  // weight repack (bf16, B^T layouts; Wout_t zero-padded to 128 rows)
  hipMemsetAsync(Wout_t, 0, 128 * E_DIM * 2, stream);
  repack_qkv<<<3456, 256, 0, stream>>>(Wq, Wqkv_t, 0);
  repack_qkv<<<3456, 256, 0, stream>>>(Wk, Wqkv_t, 384);
  repack_qkv<<<3456, 256, 0, stream>>>(Wv, Wqkv_t, 768);
  transpose_b<<<dim3(576, 6),  256, 0, stream>>>(Wo,   Wo_t,   384, 384);
  transpose_b<<<dim3(2304, 6), 256, 0, stream>>>(W1,   W1_t,   384, 1536);
  transpose_b<<<dim3(2304, 6), 256, 0, stream>>>(W2,   W2_t,   1536, 384);
  transpose_b<<<dim3(98, 1),   256, 0, stream>>>(Wout, Wout_t, 384, 65);

  embed_k<<<12288, 256, 0, stream>>>(idx, tok, pos, x);

  for (int l = 0; l < NL; l++) {
    ln_k<<<8192, 256, 0, stream>>>(x, ln1s + l * E_DIM, ln1b + l * E_DIM, hb);
    gemm_bt<<<dim3(256, 9), 256, 0, stream>>>(hb, Wqkv_t + (size_t)l * QKV_N * E_DIM,
                                              384, QKV_N, nullptr, nullptr, nullptr, qkv, 0);
    attn_k<<<768, 512, 0, stream>>>(qkv, attb);
    gemm_bt<<<dim3(256, 3), 256, 0, stream>>>(attb, Wo_t + (size_t)l * E_DIM * E_DIM,
                                              384, E_DIM, bo + l * E_DIM, x, x, nullptr, 0);
    ln_k<<<8192, 256, 0, stream>>>(x, ln2s + l * E_DIM, ln2b + l * E_DIM, hb);
    gemm_bt<<<dim3(256, 12), 256, 0, stream>>>(hb, W1_t + (size_t)l * FF_DIM * E_DIM,
                                               384, FF_DIM, b1 + l * FF_DIM, nullptr, nullptr, ff, 1);
    gemm_bt<<<dim3(256, 3), 256, 0, stream>>>(ff, W2_t + (size_t)l * E_DIM * FF_DIM,
                                              1536, E_DIM, b2 + l * E_DIM, x, x, nullptr, 0);
  }
  ln_k<<<8192, 256, 0, stream>>>(x, lnfs, lnfb, hb);
  gemm_bt<<<dim3(256, 1), 256, 0, stream>>>(hb, Wout_t, 384, VOC, bout, nullptr, logits, nullptr, 0);

  hipMemsetAsync(loss, 0, 4, stream);
  loss_k<<<8192, 256, 0, stream>>>(logits, tgt, loss);
}

// Round 2
// 2239.223 us; speedup vs baseline: 1.0593x; 1.0593x over previous
//
#include <hip/hip_runtime.h>

// ---- problem constants ----
#define BT      32768     // B*T = 128*256
#define T_SEQ   256
#define E_DIM   384
#define NH      6
#define NL      6
#define VOC     65
#define FF_DIM  1536
#define QKV_N   1152      // 3*E

typedef short bf16x8 __attribute__((ext_vector_type(8)));   // 8 bf16 (4 VGPRs)
typedef float f32x4  __attribute__((ext_vector_type(4)));
typedef unsigned short u16;

typedef const unsigned int __attribute__((address_space(1))) gu32;
typedef unsigned int       __attribute__((address_space(3))) lu32;

__device__ __forceinline__ u16 f2bf(float x) {              // RNE fp32->bf16
  unsigned u = __builtin_bit_cast(unsigned, x);
  u += 0x7fffu + ((u >> 16) & 1u);
  return (u16)(u >> 16);
}

__device__ __forceinline__ void load_lds_16(const void* g, void* l) {
  __builtin_amdgcn_global_load_lds((gu32*)g, (lu32*)l, 16, 0, 0);
}

// ---------------- unified LDS-tiled transpose: src[b][R][C] fp32 -> dst bf16 [.. C][R] ----------------
// dst block offset = dbase + (b/inner)*dbs_outer + (b%inner)*dbs_inner
// 32x32 tile, +1 pad: coalesced 128B fp32 reads, coalesced 64B bf16 writes, conflict-free LDS.
__global__ __launch_bounds__(256) void transpose_t(
    const float* __restrict__ src, u16* __restrict__ dst, int R, int C,
    long sbs, long dbs_outer, int inner, long dbs_inner, long dbase) {
  __shared__ float t[32][33];
  const int b = blockIdx.z;
  const float* s = src + (long)b * sbs;
  u16* d = dst + dbase + (long)(b / inner) * dbs_outer + (long)(b % inner) * dbs_inner;
  const int r0 = blockIdx.x * 32, c0 = blockIdx.y * 32;
  const int tx = threadIdx.x & 31, ty = threadIdx.x >> 5;   // 32 x 8
#pragma unroll
  for (int i = 0; i < 4; i++) {
    int rr = ty + i * 8;
    int r = r0 + rr, c = c0 + tx;
    if (r < R && c < C) t[rr][tx] = s[(long)r * C + c];
  }
  __syncthreads();
#pragma unroll
  for (int i = 0; i < 4; i++) {
    int cc = ty + i * 8;
    int c = c0 + cc, r = r0 + tx;
    if (c < C && r < R) d[(long)c * R + r] = f2bf(t[tx][cc]);
  }
}

// ---------------- embedding ----------------
__global__ __launch_bounds__(256) void embed_k(const int* __restrict__ idx,
                                               const float* __restrict__ tok,
                                               const float* __restrict__ pos,
                                               float* __restrict__ x) {
  int i = blockIdx.x * 256 + threadIdx.x;        // over BT*96 float4s
  int bt = i / 96, q = i - bt * 96;
  int t = bt & 255;
  float4 a = ((const float4*)tok)[(size_t)idx[bt] * 96 + q];
  float4 p = ((const float4*)pos)[(size_t)t * 96 + q];
  ((float4*)x)[i] = make_float4(a.x + p.x, a.y + p.y, a.z + p.z, a.w + p.w);
}

// ---------------- layernorm (fp32 in -> bf16 out) ----------------
__global__ __launch_bounds__(256) void ln_k(const float* __restrict__ x,
                                            const float* __restrict__ gam,
                                            const float* __restrict__ bet,
                                            u16* __restrict__ out) {
  int tid = threadIdx.x, lane = tid & 63, w = tid >> 6;
  size_t token = (size_t)blockIdx.x * 4 + w;
  const float* xr = x + token * E_DIM;
  float v[6]; float s = 0.f;
#pragma unroll
  for (int i = 0; i < 6; i++) { v[i] = xr[i * 64 + lane]; s += v[i]; }
#pragma unroll
  for (int d = 1; d < 64; d <<= 1) s += __shfl_xor(s, d);
  float mean = s * (1.f / E_DIM);
  float q = 0.f;
#pragma unroll
  for (int i = 0; i < 6; i++) { float d0 = v[i] - mean; q += d0 * d0; }
#pragma unroll
  for (int d = 1; d < 64; d <<= 1) q += __shfl_xor(q, d);
  float r = rsqrtf(q * (1.f / E_DIM) + 1e-5f);
#pragma unroll
  for (int i = 0; i < 6; i++) {
    int e = i * 64 + lane;
    out[token * E_DIM + e] = f2bf((v[i] - mean) * r * gam[e] + bet[e]);
  }
}

// ---------------- MFMA GEMM: C[M][N] = A[M][K](bf16) @ Bt[N][K](bf16)^T ----------------
// 128x128 tile, BK=32, 4 waves in 2x2, 4x4 16x16x32 MFMA per wave. m97 structure.
__global__ __launch_bounds__(256) void gemm_bt(
    const u16* __restrict__ A, const u16* __restrict__ Bt, int K, int Nstore,
    const float* __restrict__ bias, const float* __restrict__ resid,
    float* __restrict__ outF, u16* __restrict__ outH, int relu) {
  __shared__ u16 As[128 * 32];
  __shared__ u16 Bs[128 * 32];
  const int tid = threadIdx.x, lane = tid & 63, wv = tid >> 6;
  const int quad = lane >> 4, l16 = lane & 15;
  const int m0 = blockIdx.x * 128, n0 = blockIdx.y * 128;
  const int wm = (wv & 1) * 64, wn = (wv >> 1) * 64;
  const int srow = lane >> 2, scol = (lane & 3) * 8;

  f32x4 acc[4][4];
#pragma unroll
  for (int i = 0; i < 4; i++)
#pragma unroll
    for (int j = 0; j < 4; j++) acc[i][j] = (f32x4){0.f, 0.f, 0.f, 0.f};

  for (int k0 = 0; k0 < K; k0 += 32) {
    __syncthreads();
#pragma unroll
    for (int j = 0; j < 2; j++) {
      int rid = wv * 2 + j;
      int r = rid * 16 + srow;
      load_lds_16(A  + (size_t)(m0 + r) * K + (k0 + scol), &As[rid * 512]);
      load_lds_16(Bt + (size_t)(n0 + r) * K + (k0 + scol), &Bs[rid * 512]);
    }
    __syncthreads();
    bf16x8 af[4], bfr[4];
#pragma unroll
    for (int i = 0; i < 4; i++) af[i]  = *(const bf16x8*)&As[(wm + i * 16 + l16) * 32 + quad * 8];
#pragma unroll
    for (int j = 0; j < 4; j++) bfr[j] = *(const bf16x8*)&Bs[(wn + j * 16 + l16) * 32 + quad * 8];
#pragma unroll
    for (int i = 0; i < 4; i++)
#pragma unroll
      for (int j = 0; j < 4; j++)
        acc[i][j] = __builtin_amdgcn_mfma_f32_16x16x32_bf16(af[i], bfr[j], acc[i][j], 0, 0, 0);
  }

  // epilogue: C/D layout row = quad*4+reg, col = lane&15
#pragma unroll
  for (int j = 0; j < 4; j++) {
    const int gn = n0 + wn + j * 16 + l16;
    if (gn < Nstore) {
      const float bv = bias ? bias[gn] : 0.f;
#pragma unroll
      for (int i = 0; i < 4; i++) {
#pragma unroll
        for (int r = 0; r < 4; r++) {
          const int gm = m0 + wm + i * 16 + quad * 4 + r;
          float v = acc[i][j][r] + bv;
          if (relu) v = fmaxf(v, 0.f);
          const size_t o = (size_t)gm * Nstore + gn;
          if (outF) outF[o] = v + (resid ? resid[o] : 0.f);
          else      outH[o] = f2bf(v);
        }
      }
    }
  }
}

// ---------------- fused causal attention ----------------
__global__ __launch_bounds__(512) void attn_k(const u16* __restrict__ qkv,
                                              u16* __restrict__ att) {
  __shared__ u16 Kc[64 * 64];
  __shared__ u16 Vtc[64 * 64];
  __shared__ u16 Pl[8 * 32 * 64];
  const int b = blockIdx.x / NH, h = blockIdx.x % NH;
  const int tid = threadIdx.x, lane = tid & 63, w = tid >> 6;
  const int quad = lane >> 4, l16 = lane & 15;
  const int rowb = b * T_SEQ;

  bf16x8 qf[2][2];
#pragma unroll
  for (int mi = 0; mi < 2; mi++)
#pragma unroll
    for (int kk = 0; kk < 2; kk++)
      qf[mi][kk] = *(const bf16x8*)(qkv + (size_t)(rowb + w * 32 + mi * 16 + l16) * QKV_N +
                                    h * 64 + kk * 32 + quad * 8);

  f32x4 Oa[2][4];
  float mrun[2][4], lrun[2][4];
#pragma unroll
  for (int mi = 0; mi < 2; mi++) {
#pragma unroll
    for (int di = 0; di < 4; di++) Oa[mi][di] = (f32x4){0.f, 0.f, 0.f, 0.f};
#pragma unroll
    for (int r = 0; r < 4; r++) { mrun[mi][r] = -1e30f; lrun[mi][r] = 0.f; }
  }

  u16* Pw = &Pl[w * 2048];
  const int nch = (w >> 1) + 1;
  const int sr = tid >> 3, sseg = (tid & 7) * 8;

  for (int c = 0; c < 4; c++) {
    const int s0 = c * 64;
    __syncthreads();
    *(uint4*)&Kc[sr * 64 + sseg] =
        *(const uint4*)(qkv + (size_t)(rowb + s0 + sr) * QKV_N + 384 + h * 64 + sseg);
    {
      union { uint4 u; u16 us[8]; } tb;
      tb.u = *(const uint4*)(qkv + (size_t)(rowb + s0 + sr) * QKV_N + 768 + h * 64 + sseg);
#pragma unroll
      for (int j = 0; j < 8; j++) Vtc[(sseg + j) * 64 + sr] = tb.us[j];
    }
    __syncthreads();
    if (c >= nch) continue;

    f32x4 S[2][4];
    bf16x8 kf[4][2];
#pragma unroll
    for (int ni = 0; ni < 4; ni++)
#pragma unroll
      for (int kk = 0; kk < 2; kk++)
        kf[ni][kk] = *(const bf16x8*)&Kc[(ni * 16 + l16) * 64 + kk * 32 + quad * 8];
#pragma unroll
    for (int mi = 0; mi < 2; mi++)
#pragma unroll
      for (int ni = 0; ni < 4; ni++) {
        f32x4 z = (f32x4){0.f, 0.f, 0.f, 0.f};
        z = __builtin_amdgcn_mfma_f32_16x16x32_bf16(qf[mi][0], kf[ni][0], z, 0, 0, 0);
        S[mi][ni] = __builtin_amdgcn_mfma_f32_16x16x32_bf16(qf[mi][1], kf[ni][1], z, 0, 0, 0);
      }
    const bool diag = (c == nch - 1);
#pragma unroll
    for (int mi = 0; mi < 2; mi++)
#pragma unroll
      for (int ni = 0; ni < 4; ni++)
#pragma unroll
        for (int r = 0; r < 4; r++) {
          float xv = S[mi][ni][r] * 0.125f;
          if (diag) {
            int t = w * 32 + mi * 16 + quad * 4 + r;
            int s = s0 + ni * 16 + l16;
            if (s > t) xv = -1e30f;
          }
          S[mi][ni][r] = xv;
        }
#pragma unroll
    for (int mi = 0; mi < 2; mi++)
#pragma unroll
      for (int r = 0; r < 4; r++) {
        float mx = fmaxf(fmaxf(S[mi][0][r], S[mi][1][r]), fmaxf(S[mi][2][r], S[mi][3][r]));
        mx = fmaxf(mx, __shfl_xor(mx, 1));
        mx = fmaxf(mx, __shfl_xor(mx, 2));
        mx = fmaxf(mx, __shfl_xor(mx, 4));
        mx = fmaxf(mx, __shfl_xor(mx, 8));
        float mnew = fmaxf(mrun[mi][r], mx);
        float alpha = __expf(mrun[mi][r] - mnew);
        float ls = 0.f;
#pragma unroll
        for (int ni = 0; ni < 4; ni++) {
          float p = __expf(S[mi][ni][r] - mnew);
          S[mi][ni][r] = p; ls += p;
        }
        ls += __shfl_xor(ls, 1); ls += __shfl_xor(ls, 2);
        ls += __shfl_xor(ls, 4); ls += __shfl_xor(ls, 8);
        lrun[mi][r] = lrun[mi][r] * alpha + ls;
        mrun[mi][r] = mnew;
#pragma unroll
        for (int di = 0; di < 4; di++) Oa[mi][di][r] *= alpha;
      }
#pragma unroll
    for (int mi = 0; mi < 2; mi++)
#pragma unroll
      for (int ni = 0; ni < 4; ni++)
#pragma unroll
        for (int r = 0; r < 4; r++)
          Pw[(mi * 16 + quad * 4 + r) * 64 + ni * 16 + l16] = f2bf(S[mi][ni][r]);
    bf16x8 pf[2][2], vf[4][2];
#pragma unroll
    for (int mi = 0; mi < 2; mi++)
#pragma unroll
      for (int kk = 0; kk < 2; kk++)
        pf[mi][kk] = *(const bf16x8*)&Pw[(mi * 16 + l16) * 64 + kk * 32 + quad * 8];
#pragma unroll
    for (int di = 0; di < 4; di++)
#pragma unroll
      for (int kk = 0; kk < 2; kk++)
        vf[di][kk] = *(const bf16x8*)&Vtc[(di * 16 + l16) * 64 + kk * 32 + quad * 8];
#pragma unroll
    for (int mi = 0; mi < 2; mi++)
#pragma unroll
      for (int di = 0; di < 4; di++) {
        Oa[mi][di] = __builtin_amdgcn_mfma_f32_16x16x32_bf16(pf[mi][0], vf[di][0], Oa[mi][di], 0, 0, 0);
        Oa[mi][di] = __builtin_amdgcn_mfma_f32_16x16x32_bf16(pf[mi][1], vf[di][1], Oa[mi][di], 0, 0, 0);
      }
  }

#pragma unroll
  for (int mi = 0; mi < 2; mi++)
#pragma unroll
    for (int r = 0; r < 4; r++) {
      float inv = 1.f / lrun[mi][r];
      int t = w * 32 + mi * 16 + quad * 4 + r;
#pragma unroll
      for (int di = 0; di < 4; di++)
        att[(size_t)(rowb + t) * E_DIM + h * 64 + di * 16 + l16] = f2bf(Oa[mi][di][r] * inv);
    }
}

// ---------------- loss: grid-stride, 1 atomic per block (512 total, was 8192) ----------------
__global__ __launch_bounds__(256) void loss_k(const float* __restrict__ logits,
                                              const int* __restrict__ tgt,
                                              float* __restrict__ loss) {
  __shared__ float part[4];
  const int tid = threadIdx.x, lane = tid & 63, w = tid >> 6;
  const int wave_id = blockIdx.x * 4 + w;          // 512 blocks -> 2048 waves
  float acc = 0.f;
  for (int t = wave_id; t < BT; t += 2048) {
    const float* row = logits + (size_t)t * VOC;
    float a = row[lane];
    float b = (lane == 0) ? row[64] : -1e30f;
    float mx = fmaxf(a, b);
#pragma unroll
    for (int d = 1; d < 64; d <<= 1) mx = fmaxf(mx, __shfl_xor(mx, d));
    float sum = __expf(a - mx) + ((lane == 0) ? __expf(b - mx) : 0.f);
#pragma unroll
    for (int d = 1; d < 64; d <<= 1) sum += __shfl_xor(sum, d);
    if (lane == 0) acc += mx + __logf(sum) - row[tgt[t]];
  }
  if (lane == 0) part[w] = acc;
  __syncthreads();
  if (tid == 0)
    atomicAdd(loss, (part[0] + part[1] + part[2] + part[3]) * (1.f / (float)BT));
}

// ---------------- host ----------------
extern "C" void kernel_launch(void* const* d_in, const int* in_sizes, int n_in,
                              void* d_out, int out_size, void* d_ws, size_t ws_size,
                              hipStream_t stream) {
  (void)in_sizes; (void)n_in; (void)out_size; (void)ws_size;
  const int*   idx  = (const int*)d_in[0];
  const int*   tgt  = (const int*)d_in[1];
  const float* tok  = (const float*)d_in[2];
  const float* pos  = (const float*)d_in[3];
  const float* Wq   = (const float*)d_in[4];
  const float* Wk   = (const float*)d_in[5];
  const float* Wv   = (const float*)d_in[6];
  const float* Wo   = (const float*)d_in[7];
  const float* bo   = (const float*)d_in[8];
  const float* ln1s = (const float*)d_in[9];
  const float* ln1b = (const float*)d_in[10];
  const float* ln2s = (const float*)d_in[11];
  const float* ln2b = (const float*)d_in[12];
  const float* W1   = (const float*)d_in[13];
  const float* b1   = (const float*)d_in[14];
  const float* W2   = (const float*)d_in[15];
  const float* b2   = (const float*)d_in[16];
  const float* lnfs = (const float*)d_in[17];
  const float* lnfb = (const float*)d_in[18];
  const float* Wout = (const float*)d_in[19];
  const float* bout = (const float*)d_in[20];

  char* w = (char*)d_ws;
  float* x    = (float*)w;  w += (size_t)BT * E_DIM * 4;
  u16* hb     = (u16*)w;    w += (size_t)BT * E_DIM * 2;
  u16* attb   = (u16*)w;    w += (size_t)BT * E_DIM * 2;
  u16* big    = (u16*)w;    w += (size_t)BT * FF_DIM * 2;     // qkv / ff union
  u16* Wqkv_t = (u16*)w;    w += (size_t)NL * QKV_N * E_DIM * 2;
  u16* Wo_t   = (u16*)w;    w += (size_t)NL * E_DIM * E_DIM * 2;
  u16* W1_t   = (u16*)w;    w += (size_t)NL * FF_DIM * E_DIM * 2;
  u16* W2_t   = (u16*)w;    w += (size_t)NL * E_DIM * FF_DIM * 2;
  u16* Wout_t = (u16*)w;    w += (size_t)128 * E_DIM * 2;
  u16* qkv = big;
  u16* ff  = big;

  float* logits = (float*)d_out;
  float* loss   = logits + (size_t)BT * VOC;

  // weight repack: LDS-tiled transpose, coalesced both sides.
  hipMemsetAsync(Wout_t, 0, 128 * E_DIM * 2, stream);
  // Wq/Wk/Wv: per (l,h) transpose [E=384][DH=64] -> rows rowoff+h*64.. of [L][1152][384]
  transpose_t<<<dim3(12, 2, 36), 256, 0, stream>>>(Wq, Wqkv_t, 384, 64,
      24576, 442368, 6, 24576, 0);
  transpose_t<<<dim3(12, 2, 36), 256, 0, stream>>>(Wk, Wqkv_t, 384, 64,
      24576, 442368, 6, 24576, (long)384 * 384);
  transpose_t<<<dim3(12, 2, 36), 256, 0, stream>>>(Wv, Wqkv_t, 384, 64,
      24576, 442368, 6, 24576, (long)768 * 384);
  transpose_t<<<dim3(12, 12, 6), 256, 0, stream>>>(Wo, Wo_t, 384, 384,
      147456, 147456, 1, 0, 0);
  transpose_t<<<dim3(12, 48, 6), 256, 0, stream>>>(W1, W1_t, 384, 1536,
      589824, 589824, 1, 0, 0);
  transpose_t<<<dim3(48, 12, 6), 256, 0, stream>>>(W2, W2_t, 1536, 384,
      589824, 589824, 1, 0, 0);
  transpose_t<<<dim3(12, 3, 1), 256, 0, stream>>>(Wout, Wout_t, 384, 65,
      0, 0, 1, 0, 0);

  embed_k<<<12288, 256, 0, stream>>>(idx, tok, pos, x);

  for (int l = 0; l < NL; l++) {
    ln_k<<<8192, 256, 0, stream>>>(x, ln1s + l * E_DIM, ln1b + l * E_DIM, hb);
    gemm_bt<<<dim3(256, 9), 256, 0, stream>>>(hb, Wqkv_t + (size_t)l * QKV_N * E_DIM,
                                              384, QKV_N, nullptr, nullptr, nullptr, qkv, 0);
    attn_k<<<768, 512, 0, stream>>>(qkv, attb);
    gemm_bt<<<dim3(256, 3), 256, 0, stream>>>(attb, Wo_t + (size_t)l * E_DIM * E_DIM,
                                              384, E_DIM, bo + l * E_DIM, x, x, nullptr, 0);
    ln_k<<<8192, 256, 0, stream>>>(x, ln2s + l * E_DIM, ln2b + l * E_DIM, hb);
    gemm_bt<<<dim3(256, 12), 256, 0, stream>>>(hb, W1_t + (size_t)l * FF_DIM * E_DIM,
                                               384, FF_DIM, b1 + l * FF_DIM, nullptr, nullptr, ff, 1);
    gemm_bt<<<dim3(256, 3), 256, 0, stream>>>(ff, W2_t + (size_t)l * E_DIM * FF_DIM,
                                              1536, E_DIM, b2 + l * E_DIM, x, x, nullptr, 0);
  }
  ln_k<<<8192, 256, 0, stream>>>(x, lnfs, lnfb, hb);
  gemm_bt<<<dim3(256, 1), 256, 0, stream>>>(hb, Wout_t, 384, VOC, bout, nullptr, logits, nullptr, 0);

  hipMemsetAsync(loss, 0, 4, stream);
  loss_k<<<512, 256, 0, stream>>>(logits, tgt, loss);
}

// Round 3
// 1912.345 us; speedup vs baseline: 1.2404x; 1.1709x over previous
//
#include <hip/hip_runtime.h>

// ---- problem constants ----
#define BT      32768     // B*T = 128*256
#define T_SEQ   256
#define E_DIM   384
#define NH      6
#define NL      6
#define VOC     65
#define FF_DIM  1536
#define QKV_N   1152      // 3*E

typedef short bf16x8 __attribute__((ext_vector_type(8)));   // 8 bf16 (4 VGPRs)
typedef float f32x4  __attribute__((ext_vector_type(4)));
typedef unsigned short u16;

typedef const unsigned int __attribute__((address_space(1))) gu32;
typedef unsigned int       __attribute__((address_space(3))) lu32;

__device__ __forceinline__ u16 f2bf(float x) {              // RNE fp32->bf16
  unsigned u = __builtin_bit_cast(unsigned, x);
  u += 0x7fffu + ((u >> 16) & 1u);
  return (u16)(u >> 16);
}
__device__ __forceinline__ float bf2f(u16 v) {
  unsigned u = ((unsigned)v) << 16;
  return __builtin_bit_cast(float, u);
}

__device__ __forceinline__ void load_lds_16(const void* g, void* l) {
  __builtin_amdgcn_global_load_lds((gu32*)g, (lu32*)l, 16, 0, 0);
}

// ---------------- unified LDS-tiled transpose: src[b][R][C] fp32 -> dst bf16 [.. C][R] ----------------
__global__ __launch_bounds__(256) void transpose_t(
    const float* __restrict__ src, u16* __restrict__ dst, int R, int C,
    long sbs, long dbs_outer, int inner, long dbs_inner, long dbase) {
  __shared__ float t[32][33];
  const int b = blockIdx.z;
  const float* s = src + (long)b * sbs;
  u16* d = dst + dbase + (long)(b / inner) * dbs_outer + (long)(b % inner) * dbs_inner;
  const int r0 = blockIdx.x * 32, c0 = blockIdx.y * 32;
  const int tx = threadIdx.x & 31, ty = threadIdx.x >> 5;   // 32 x 8
#pragma unroll
  for (int i = 0; i < 4; i++) {
    int rr = ty + i * 8;
    int r = r0 + rr, c = c0 + tx;
    if (r < R && c < C) t[rr][tx] = s[(long)r * C + c];
  }
  __syncthreads();
#pragma unroll
  for (int i = 0; i < 4; i++) {
    int cc = ty + i * 8;
    int c = c0 + cc, r = r0 + tx;
    if (c < C && r < R) d[(long)c * R + r] = f2bf(t[tx][cc]);
  }
}

// ---------------- embedding (bf16 out) ----------------
__global__ __launch_bounds__(256) void embed_k(const int* __restrict__ idx,
                                               const float* __restrict__ tok,
                                               const float* __restrict__ pos,
                                               u16* __restrict__ x) {
  int i = blockIdx.x * 256 + threadIdx.x;        // over BT*48 groups of 8
  int bt = i / 48, q = i - bt * 48;
  int t = bt & 255;
  const float4* tp = (const float4*)(tok + (size_t)idx[bt] * E_DIM + q * 8);
  const float4* pp = (const float4*)(pos + (size_t)t * E_DIM + q * 8);
  float4 a0 = tp[0], a1 = tp[1], p0 = pp[0], p1 = pp[1];
  u16 o[8];
  o[0] = f2bf(a0.x + p0.x); o[1] = f2bf(a0.y + p0.y);
  o[2] = f2bf(a0.z + p0.z); o[3] = f2bf(a0.w + p0.w);
  o[4] = f2bf(a1.x + p1.x); o[5] = f2bf(a1.y + p1.y);
  o[6] = f2bf(a1.z + p1.z); o[7] = f2bf(a1.w + p1.w);
  *(bf16x8*)(x + (size_t)bt * E_DIM + q * 8) = *(bf16x8*)o;
}

// ---------------- layernorm (bf16 in -> bf16 out, fp32 math) ----------------
__global__ __launch_bounds__(256) void ln_k(const u16* __restrict__ x,
                                            const float* __restrict__ gam,
                                            const float* __restrict__ bet,
                                            u16* __restrict__ out) {
  int tid = threadIdx.x, lane = tid & 63, w = tid >> 6;
  size_t token = (size_t)blockIdx.x * 4 + w;
  const u16* xr = x + token * E_DIM;
  u16 raw[6];
  *(uint2*)raw          = *(const uint2*)(xr + 4 * lane);           // elems 4L..4L+3
  *(unsigned*)(raw + 4) = *(const unsigned*)(xr + 256 + 2 * lane);  // elems 256+2L..+1
  float v[6]; float s = 0.f;
#pragma unroll
  for (int i = 0; i < 6; i++) { v[i] = bf2f(raw[i]); s += v[i]; }
#pragma unroll
  for (int d = 1; d < 64; d <<= 1) s += __shfl_xor(s, d);
  float mean = s * (1.f / E_DIM);
  float q = 0.f;
#pragma unroll
  for (int i = 0; i < 6; i++) { float d0 = v[i] - mean; q += d0 * d0; }
#pragma unroll
  for (int d = 1; d < 64; d <<= 1) q += __shfl_xor(q, d);
  float r = rsqrtf(q * (1.f / E_DIM) + 1e-5f);
  int e[6] = {4 * lane, 4 * lane + 1, 4 * lane + 2, 4 * lane + 3,
              256 + 2 * lane, 256 + 2 * lane + 1};
  u16 o[6];
#pragma unroll
  for (int i = 0; i < 6; i++)
    o[i] = f2bf((v[i] - mean) * r * gam[e[i]] + bet[e[i]]);
  u16* orow = out + token * E_DIM;
  *(uint2*)(orow + 4 * lane)        = *(uint2*)o;
  *(unsigned*)(orow + 256 + 2 * lane) = *(unsigned*)(o + 4);
}

// ---------------- MFMA GEMM: C[M][N] = A[M][K](bf16) @ Bt[N][K](bf16)^T ----------------
// 128x128 tile, BK=32, 4 waves 2x2, 4x4 16x16x32 MFMA per wave.
// outH path: coalesced LDS-repacked bf16 stores (requires Nstore%128==0), optional bf16 resid.
// outF path: scalar fp32 stores with gn<Nstore guard (logits only).
__global__ __launch_bounds__(256) void gemm_bt(
    const u16* __restrict__ A, const u16* __restrict__ Bt, int K, int Nstore,
    const float* __restrict__ bias, const u16* __restrict__ resid,
    u16* __restrict__ outH, float* __restrict__ outF, int relu) {
  __shared__ u16 smem[8192];            // As 128x32 | Bs 128x32 ; epilogue: cbuf 128x36
  u16* As = smem;
  u16* Bs = smem + 4096;
  const int tid = threadIdx.x, lane = tid & 63, wv = tid >> 6;
  const int quad = lane >> 4, l16 = lane & 15;
  const int m0 = blockIdx.x * 128, n0 = blockIdx.y * 128;
  const int wm = (wv & 1) * 64, wn = (wv >> 1) * 64;
  const int srow = lane >> 2, scol = (lane & 3) * 8;

  f32x4 acc[4][4];
#pragma unroll
  for (int i = 0; i < 4; i++)
#pragma unroll
    for (int j = 0; j < 4; j++) acc[i][j] = (f32x4){0.f, 0.f, 0.f, 0.f};

  for (int k0 = 0; k0 < K; k0 += 32) {
    __syncthreads();
#pragma unroll
    for (int j = 0; j < 2; j++) {
      int rid = wv * 2 + j;
      int r = rid * 16 + srow;
      load_lds_16(A  + (size_t)(m0 + r) * K + (k0 + scol), &As[rid * 512]);
      load_lds_16(Bt + (size_t)(n0 + r) * K + (k0 + scol), &Bs[rid * 512]);
    }
    __syncthreads();
    bf16x8 af[4], bfr[4];
#pragma unroll
    for (int i = 0; i < 4; i++) af[i]  = *(const bf16x8*)&As[(wm + i * 16 + l16) * 32 + quad * 8];
#pragma unroll
    for (int j = 0; j < 4; j++) bfr[j] = *(const bf16x8*)&Bs[(wn + j * 16 + l16) * 32 + quad * 8];
#pragma unroll
    for (int i = 0; i < 4; i++)
#pragma unroll
      for (int j = 0; j < 4; j++)
        acc[i][j] = __builtin_amdgcn_mfma_f32_16x16x32_bf16(af[i], bfr[j], acc[i][j], 0, 0, 0);
  }

  if (outH) {
    // 4 passes of 32 columns; each pass: matching-wn waves deposit C-layout values
    // into cbuf[128][36] (pad 36 -> quad rows land on disjoint banks), then the
    // whole block sweeps out 64B-per-row coalesced stores, fusing resid add.
#pragma unroll
    for (int p = 0; p < 4; p++) {
      __syncthreads();
      if ((wv >> 1) == (p >> 1)) {
#pragma unroll
        for (int jj = 0; jj < 2; jj++) {
          int j = (p & 1) * 2 + jj;
          int gn = n0 + wn + j * 16 + l16;
          float bv = bias ? bias[gn] : 0.f;
          int lcol = jj * 16 + l16;
#pragma unroll
          for (int i = 0; i < 4; i++)
#pragma unroll
            for (int r = 0; r < 4; r++) {
              float v = acc[i][j][r] + bv;
              if (relu) v = fmaxf(v, 0.f);
              smem[(wm + i * 16 + quad * 4 + r) * 36 + lcol] = f2bf(v);
            }
        }
      }
      __syncthreads();
      const int gc0 = n0 + p * 32;
#pragma unroll
      for (int s = 0; s < 4; s++) {
        int row = s * 32 + (tid >> 3);
        int seg = (tid & 7) * 4;
        u16 pk[4];
        *(uint2*)pk = *(const uint2*)&smem[row * 36 + seg];
        size_t o = (size_t)(m0 + row) * Nstore + gc0 + seg;
        if (resid) {
          u16 rv[4];
          *(uint2*)rv = *(const uint2*)&resid[o];
#pragma unroll
          for (int q2 = 0; q2 < 4; q2++) pk[q2] = f2bf(bf2f(pk[q2]) + bf2f(rv[q2]));
        }
        *(uint2*)&outH[o] = *(uint2*)pk;
      }
    }
  } else {
    // fp32 path (logits, N=65)
#pragma unroll
    for (int j = 0; j < 4; j++) {
      const int gn = n0 + wn + j * 16 + l16;
      if (gn < Nstore) {
        const float bv = bias ? bias[gn] : 0.f;
#pragma unroll
        for (int i = 0; i < 4; i++)
#pragma unroll
          for (int r = 0; r < 4; r++) {
            const int gm = m0 + wm + i * 16 + quad * 4 + r;
            outF[(size_t)gm * Nstore + gn] = acc[i][j][r] + bv;
          }
      }
    }
  }
}

// ---------------- fused causal attention ----------------
__global__ __launch_bounds__(512) void attn_k(const u16* __restrict__ qkv,
                                              u16* __restrict__ att) {
  __shared__ u16 Kc[64 * 64];
  __shared__ u16 Vtc[64 * 64];
  __shared__ u16 Pl[8 * 32 * 64];
  const int b = blockIdx.x / NH, h = blockIdx.x % NH;
  const int tid = threadIdx.x, lane = tid & 63, w = tid >> 6;
  const int quad = lane >> 4, l16 = lane & 15;
  const int rowb = b * T_SEQ;

  bf16x8 qf[2][2];
#pragma unroll
  for (int mi = 0; mi < 2; mi++)
#pragma unroll
    for (int kk = 0; kk < 2; kk++)
      qf[mi][kk] = *(const bf16x8*)(qkv + (size_t)(rowb + w * 32 + mi * 16 + l16) * QKV_N +
                                    h * 64 + kk * 32 + quad * 8);

  f32x4 Oa[2][4];
  float mrun[2][4], lrun[2][4];
#pragma unroll
  for (int mi = 0; mi < 2; mi++) {
#pragma unroll
    for (int di = 0; di < 4; di++) Oa[mi][di] = (f32x4){0.f, 0.f, 0.f, 0.f};
#pragma unroll
    for (int r = 0; r < 4; r++) { mrun[mi][r] = -1e30f; lrun[mi][r] = 0.f; }
  }

  u16* Pw = &Pl[w * 2048];
  const int nch = (w >> 1) + 1;
  const int sr = tid >> 3, sseg = (tid & 7) * 8;

  for (int c = 0; c < 4; c++) {
    const int s0 = c * 64;
    __syncthreads();
    *(uint4*)&Kc[sr * 64 + sseg] =
        *(const uint4*)(qkv + (size_t)(rowb + s0 + sr) * QKV_N + 384 + h * 64 + sseg);
    {
      union { uint4 u; u16 us[8]; } tb;
      tb.u = *(const uint4*)(qkv + (size_t)(rowb + s0 + sr) * QKV_N + 768 + h * 64 + sseg);
#pragma unroll
      for (int j = 0; j < 8; j++) Vtc[(sseg + j) * 64 + sr] = tb.us[j];
    }
    __syncthreads();
    if (c >= nch) continue;

    f32x4 S[2][4];
    bf16x8 kf[4][2];
#pragma unroll
    for (int ni = 0; ni < 4; ni++)
#pragma unroll
      for (int kk = 0; kk < 2; kk++)
        kf[ni][kk] = *(const bf16x8*)&Kc[(ni * 16 + l16) * 64 + kk * 32 + quad * 8];
#pragma unroll
    for (int mi = 0; mi < 2; mi++)
#pragma unroll
      for (int ni = 0; ni < 4; ni++) {
        f32x4 z = (f32x4){0.f, 0.f, 0.f, 0.f};
        z = __builtin_amdgcn_mfma_f32_16x16x32_bf16(qf[mi][0], kf[ni][0], z, 0, 0, 0);
        S[mi][ni] = __builtin_amdgcn_mfma_f32_16x16x32_bf16(qf[mi][1], kf[ni][1], z, 0, 0, 0);
      }
    const bool diag = (c == nch - 1);
#pragma unroll
    for (int mi = 0; mi < 2; mi++)
#pragma unroll
      for (int ni = 0; ni < 4; ni++)
#pragma unroll
        for (int r = 0; r < 4; r++) {
          float xv = S[mi][ni][r] * 0.125f;
          if (diag) {
            int t = w * 32 + mi * 16 + quad * 4 + r;
            int s = s0 + ni * 16 + l16;
            if (s > t) xv = -1e30f;
          }
          S[mi][ni][r] = xv;
        }
#pragma unroll
    for (int mi = 0; mi < 2; mi++)
#pragma unroll
      for (int r = 0; r < 4; r++) {
        float mx = fmaxf(fmaxf(S[mi][0][r], S[mi][1][r]), fmaxf(S[mi][2][r], S[mi][3][r]));
        mx = fmaxf(mx, __shfl_xor(mx, 1));
        mx = fmaxf(mx, __shfl_xor(mx, 2));
        mx = fmaxf(mx, __shfl_xor(mx, 4));
        mx = fmaxf(mx, __shfl_xor(mx, 8));
        float mnew = fmaxf(mrun[mi][r], mx);
        float alpha = __expf(mrun[mi][r] - mnew);
        float ls = 0.f;
#pragma unroll
        for (int ni = 0; ni < 4; ni++) {
          float p = __expf(S[mi][ni][r] - mnew);
          S[mi][ni][r] = p; ls += p;
        }
        ls += __shfl_xor(ls, 1); ls += __shfl_xor(ls, 2);
        ls += __shfl_xor(ls, 4); ls += __shfl_xor(ls, 8);
        lrun[mi][r] = lrun[mi][r] * alpha + ls;
        mrun[mi][r] = mnew;
#pragma unroll
        for (int di = 0; di < 4; di++) Oa[mi][di][r] *= alpha;
      }
#pragma unroll
    for (int mi = 0; mi < 2; mi++)
#pragma unroll
      for (int ni = 0; ni < 4; ni++)
#pragma unroll
        for (int r = 0; r < 4; r++)
          Pw[(mi * 16 + quad * 4 + r) * 64 + ni * 16 + l16] = f2bf(S[mi][ni][r]);
    bf16x8 pf[2][2], vf[4][2];
#pragma unroll
    for (int mi = 0; mi < 2; mi++)
#pragma unroll
      for (int kk = 0; kk < 2; kk++)
        pf[mi][kk] = *(const bf16x8*)&Pw[(mi * 16 + l16) * 64 + kk * 32 + quad * 8];
#pragma unroll
    for (int di = 0; di < 4; di++)
#pragma unroll
      for (int kk = 0; kk < 2; kk++)
        vf[di][kk] = *(const bf16x8*)&Vtc[(di * 16 + l16) * 64 + kk * 32 + quad * 8];
#pragma unroll
    for (int mi = 0; mi < 2; mi++)
#pragma unroll
      for (int di = 0; di < 4; di++) {
        Oa[mi][di] = __builtin_amdgcn_mfma_f32_16x16x32_bf16(pf[mi][0], vf[di][0], Oa[mi][di], 0, 0, 0);
        Oa[mi][di] = __builtin_amdgcn_mfma_f32_16x16x32_bf16(pf[mi][1], vf[di][1], Oa[mi][di], 0, 0, 0);
      }
  }

#pragma unroll
  for (int mi = 0; mi < 2; mi++)
#pragma unroll
    for (int r = 0; r < 4; r++) {
      float inv = 1.f / lrun[mi][r];
      int t = w * 32 + mi * 16 + quad * 4 + r;
#pragma unroll
      for (int di = 0; di < 4; di++)
        att[(size_t)(rowb + t) * E_DIM + h * 64 + di * 16 + l16] = f2bf(Oa[mi][di][r] * inv);
    }
}

// ---------------- loss: grid-stride, 1 atomic per block ----------------
__global__ __launch_bounds__(256) void loss_k(const float* __restrict__ logits,
                                              const int* __restrict__ tgt,
                                              float* __restrict__ loss) {
  __shared__ float part[4];
  const int tid = threadIdx.x, lane = tid & 63, w = tid >> 6;
  const int wave_id = blockIdx.x * 4 + w;          // 512 blocks -> 2048 waves
  float acc = 0.f;
  for (int t = wave_id; t < BT; t += 2048) {
    const float* row = logits + (size_t)t * VOC;
    float a = row[lane];
    float b = (lane == 0) ? row[64] : -1e30f;
    float mx = fmaxf(a, b);
#pragma unroll
    for (int d = 1; d < 64; d <<= 1) mx = fmaxf(mx, __shfl_xor(mx, d));
    float sum = __expf(a - mx) + ((lane == 0) ? __expf(b - mx) : 0.f);
#pragma unroll
    for (int d = 1; d < 64; d <<= 1) sum += __shfl_xor(sum, d);
    if (lane == 0) acc += mx + __logf(sum) - row[tgt[t]];
  }
  if (lane == 0) part[w] = acc;
  __syncthreads();
  if (tid == 0)
    atomicAdd(loss, (part[0] + part[1] + part[2] + part[3]) * (1.f / (float)BT));
}

// ---------------- host ----------------
extern "C" void kernel_launch(void* const* d_in, const int* in_sizes, int n_in,
                              void* d_out, int out_size, void* d_ws, size_t ws_size,
                              hipStream_t stream) {
  (void)in_sizes; (void)n_in; (void)out_size; (void)ws_size;
  const int*   idx  = (const int*)d_in[0];
  const int*   tgt  = (const int*)d_in[1];
  const float* tok  = (const float*)d_in[2];
  const float* pos  = (const float*)d_in[3];
  const float* Wq   = (const float*)d_in[4];
  const float* Wk   = (const float*)d_in[5];
  const float* Wv   = (const float*)d_in[6];
  const float* Wo   = (const float*)d_in[7];
  const float* bo   = (const float*)d_in[8];
  const float* ln1s = (const float*)d_in[9];
  const float* ln1b = (const float*)d_in[10];
  const float* ln2s = (const float*)d_in[11];
  const float* ln2b = (const float*)d_in[12];
  const float* W1   = (const float*)d_in[13];
  const float* b1   = (const float*)d_in[14];
  const float* W2   = (const float*)d_in[15];
  const float* b2   = (const float*)d_in[16];
  const float* lnfs = (const float*)d_in[17];
  const float* lnfb = (const float*)d_in[18];
  const float* Wout = (const float*)d_in[19];
  const float* bout = (const float*)d_in[20];

  char* w = (char*)d_ws;
  u16* x      = (u16*)w;    w += (size_t)BT * E_DIM * 2;      // bf16 residual stream
  u16* hb     = (u16*)w;    w += (size_t)BT * E_DIM * 2;
  u16* attb   = (u16*)w;    w += (size_t)BT * E_DIM * 2;
  u16* big    = (u16*)w;    w += (size_t)BT * FF_DIM * 2;     // qkv / ff union
  u16* Wqkv_t = (u16*)w;    w += (size_t)NL * QKV_N * E_DIM * 2;
  u16* Wo_t   = (u16*)w;    w += (size_t)NL * E_DIM * E_DIM * 2;
  u16* W1_t   = (u16*)w;    w += (size_t)NL * FF_DIM * E_DIM * 2;
  u16* W2_t   = (u16*)w;    w += (size_t)NL * E_DIM * FF_DIM * 2;
  u16* Wout_t = (u16*)w;    w += (size_t)128 * E_DIM * 2;
  u16* qkv = big;
  u16* ff  = big;

  float* logits = (float*)d_out;
  float* loss   = logits + (size_t)BT * VOC;

  hipMemsetAsync(Wout_t, 0, 128 * E_DIM * 2, stream);
  transpose_t<<<dim3(12, 2, 36), 256, 0, stream>>>(Wq, Wqkv_t, 384, 64,
      24576, 442368, 6, 24576, 0);
  transpose_t<<<dim3(12, 2, 36), 256, 0, stream>>>(Wk, Wqkv_t, 384, 64,
      24576, 442368, 6, 24576, (long)384 * 384);
  transpose_t<<<dim3(12, 2, 36), 256, 0, stream>>>(Wv, Wqkv_t, 384, 64,
      24576, 442368, 6, 24576, (long)768 * 384);
  transpose_t<<<dim3(12, 12, 6), 256, 0, stream>>>(Wo, Wo_t, 384, 384,
      147456, 147456, 1, 0, 0);
  transpose_t<<<dim3(12, 48, 6), 256, 0, stream>>>(W1, W1_t, 384, 1536,
      589824, 589824, 1, 0, 0);
  transpose_t<<<dim3(48, 12, 6), 256, 0, stream>>>(W2, W2_t, 1536, 384,
      589824, 589824, 1, 0, 0);
  transpose_t<<<dim3(12, 3, 1), 256, 0, stream>>>(Wout, Wout_t, 384, 65,
      0, 0, 1, 0, 0);

  embed_k<<<6144, 256, 0, stream>>>(idx, tok, pos, x);

  for (int l = 0; l < NL; l++) {
    ln_k<<<8192, 256, 0, stream>>>(x, ln1s + l * E_DIM, ln1b + l * E_DIM, hb);
    gemm_bt<<<dim3(256, 9), 256, 0, stream>>>(hb, Wqkv_t + (size_t)l * QKV_N * E_DIM,
                                              384, QKV_N, nullptr, nullptr, qkv, nullptr, 0);
    attn_k<<<768, 512, 0, stream>>>(qkv, attb);
    gemm_bt<<<dim3(256, 3), 256, 0, stream>>>(attb, Wo_t + (size_t)l * E_DIM * E_DIM,
                                              384, E_DIM, bo + l * E_DIM, x, x, nullptr, 0);
    ln_k<<<8192, 256, 0, stream>>>(x, ln2s + l * E_DIM, ln2b + l * E_DIM, hb);
    gemm_bt<<<dim3(256, 12), 256, 0, stream>>>(hb, W1_t + (size_t)l * FF_DIM * E_DIM,
                                               384, FF_DIM, b1 + l * FF_DIM, nullptr, ff, nullptr, 1);
    gemm_bt<<<dim3(256, 3), 256, 0, stream>>>(ff, W2_t + (size_t)l * E_DIM * FF_DIM,
                                              1536, E_DIM, b2 + l * E_DIM, x, x, nullptr, 0);
  }
  ln_k<<<8192, 256, 0, stream>>>(x, lnfs, lnfb, hb);
  gemm_bt<<<dim3(256, 1), 256, 0, stream>>>(hb, Wout_t, 384, VOC, bout, nullptr, nullptr, logits, 0);

  hipMemsetAsync(loss, 0, 4, stream);
  loss_k<<<512, 256, 0, stream>>>(logits, tgt, loss);
}

// Round 4
// 1866.392 us; speedup vs baseline: 1.2709x; 1.0246x over previous
//
#include <hip/hip_runtime.h>

// ---- problem constants ----
#define BT      32768     // B*T = 128*256
#define T_SEQ   256
#define E_DIM   384
#define NH      6
#define NL      6
#define VOC     65
#define FF_DIM  1536
#define QKV_N   1152      // 3*E

typedef short bf16x8 __attribute__((ext_vector_type(8)));   // 8 bf16 (4 VGPRs)
typedef float f32x4  __attribute__((ext_vector_type(4)));
typedef unsigned short u16;

typedef const unsigned int __attribute__((address_space(1))) gu32;
typedef unsigned int       __attribute__((address_space(3))) lu32;

__device__ __forceinline__ u16 f2bf(float x) {              // RNE fp32->bf16
  unsigned u = __builtin_bit_cast(unsigned, x);
  u += 0x7fffu + ((u >> 16) & 1u);
  return (u16)(u >> 16);
}
__device__ __forceinline__ float bf2f(u16 v) {
  unsigned u = ((unsigned)v) << 16;
  return __builtin_bit_cast(float, u);
}

__device__ __forceinline__ void load_lds_16(const void* g, void* l) {
  __builtin_amdgcn_global_load_lds((gu32*)g, (lu32*)l, 16, 0, 0);
}

// ---------------- unified LDS-tiled transpose: src[b][R][C] fp32 -> dst bf16 [.. C][R] ----------------
__global__ __launch_bounds__(256) void transpose_t(
    const float* __restrict__ src, u16* __restrict__ dst, int R, int C,
    long sbs, long dbs_outer, int inner, long dbs_inner, long dbase) {
  __shared__ float t[32][33];
  const int b = blockIdx.z;
  const float* s = src + (long)b * sbs;
  u16* d = dst + dbase + (long)(b / inner) * dbs_outer + (long)(b % inner) * dbs_inner;
  const int r0 = blockIdx.x * 32, c0 = blockIdx.y * 32;
  const int tx = threadIdx.x & 31, ty = threadIdx.x >> 5;   // 32 x 8
#pragma unroll
  for (int i = 0; i < 4; i++) {
    int rr = ty + i * 8;
    int r = r0 + rr, c = c0 + tx;
    if (r < R && c < C) t[rr][tx] = s[(long)r * C + c];
  }
  __syncthreads();
#pragma unroll
  for (int i = 0; i < 4; i++) {
    int cc = ty + i * 8;
    int c = c0 + cc, r = r0 + tx;
    if (c < C && r < R) d[(long)c * R + r] = f2bf(t[tx][cc]);
  }
}

// ---------------- embedding (bf16 out) ----------------
__global__ __launch_bounds__(256) void embed_k(const int* __restrict__ idx,
                                               const float* __restrict__ tok,
                                               const float* __restrict__ pos,
                                               u16* __restrict__ x) {
  int i = blockIdx.x * 256 + threadIdx.x;        // over BT*48 groups of 8
  int bt = i / 48, q = i - bt * 48;
  int t = bt & 255;
  const float4* tp = (const float4*)(tok + (size_t)idx[bt] * E_DIM + q * 8);
  const float4* pp = (const float4*)(pos + (size_t)t * E_DIM + q * 8);
  float4 a0 = tp[0], a1 = tp[1], p0 = pp[0], p1 = pp[1];
  u16 o[8];
  o[0] = f2bf(a0.x + p0.x); o[1] = f2bf(a0.y + p0.y);
  o[2] = f2bf(a0.z + p0.z); o[3] = f2bf(a0.w + p0.w);
  o[4] = f2bf(a1.x + p1.x); o[5] = f2bf(a1.y + p1.y);
  o[6] = f2bf(a1.z + p1.z); o[7] = f2bf(a1.w + p1.w);
  *(bf16x8*)(x + (size_t)bt * E_DIM + q * 8) = *(bf16x8*)o;
}

// ---------------- layernorm (bf16 in -> bf16 out, fp32 math) ----------------
__global__ __launch_bounds__(256) void ln_k(const u16* __restrict__ x,
                                            const float* __restrict__ gam,
                                            const float* __restrict__ bet,
                                            u16* __restrict__ out) {
  int tid = threadIdx.x, lane = tid & 63, w = tid >> 6;
  size_t token = (size_t)blockIdx.x * 4 + w;
  const u16* xr = x + token * E_DIM;
  u16 raw[6];
  *(uint2*)raw          = *(const uint2*)(xr + 4 * lane);
  *(unsigned*)(raw + 4) = *(const unsigned*)(xr + 256 + 2 * lane);
  float v[6]; float s = 0.f;
#pragma unroll
  for (int i = 0; i < 6; i++) { v[i] = bf2f(raw[i]); s += v[i]; }
#pragma unroll
  for (int d = 1; d < 64; d <<= 1) s += __shfl_xor(s, d);
  float mean = s * (1.f / E_DIM);
  float q = 0.f;
#pragma unroll
  for (int i = 0; i < 6; i++) { float d0 = v[i] - mean; q += d0 * d0; }
#pragma unroll
  for (int d = 1; d < 64; d <<= 1) q += __shfl_xor(q, d);
  float r = rsqrtf(q * (1.f / E_DIM) + 1e-5f);
  int e[6] = {4 * lane, 4 * lane + 1, 4 * lane + 2, 4 * lane + 3,
              256 + 2 * lane, 256 + 2 * lane + 1};
  u16 o[6];
#pragma unroll
  for (int i = 0; i < 6; i++)
    o[i] = f2bf((v[i] - mean) * r * gam[e[i]] + bet[e[i]]);
  u16* orow = out + token * E_DIM;
  *(uint2*)(orow + 4 * lane)          = *(uint2*)o;
  *(unsigned*)(orow + 256 + 2 * lane) = *(unsigned*)(o + 4);
}

// ---------------- MFMA GEMM: C[M][N] = A[M][K](bf16) @ Bt[N][K](bf16)^T ----------------
// TM x 128 tile, BK=32, 4 waves, double-buffered LDS w/ prefetch (1 barrier/iter).
// TM=256: waves 2x2 over (128m x 64n), 32 MFMA/iter/wave. TM=128: (64m x 64n), 16 MFMA.
// outH: coalesced LDS-repacked bf16 stores (+optional bf16 resid). outF: fp32 logits path.
template<int TM>
__global__ __launch_bounds__(256, TM == 256 ? 2 : 3) void gemm_bt(
    const u16* __restrict__ A, const u16* __restrict__ Bt, int K, int Nstore,
    const float* __restrict__ bias, const u16* __restrict__ resid,
    u16* __restrict__ outH, float* __restrict__ outF, int relu) {
  constexpr int MI = TM / 32;                 // MFMA row-tiles per wave
  __shared__ u16 smem[TM * 64 + 8192];        // As dbuf (TM*32 x2) | Bs dbuf (128*32 x2)
  u16* As = smem;
  u16* Bs = smem + TM * 64;
  const int tid = threadIdx.x, lane = tid & 63, wv = tid >> 6;
  const int quad = lane >> 4, l16 = lane & 15;
  const int m0 = blockIdx.x * TM, n0 = blockIdx.y * 128;
  const int wm = (wv & 1) * (TM / 2), wn = (wv >> 1) * 64;
  const int srow = lane >> 2, scol = (lane & 3) * 8;

  f32x4 acc[MI][4];
#pragma unroll
  for (int i = 0; i < MI; i++)
#pragma unroll
    for (int j = 0; j < 4; j++) acc[i][j] = (f32x4){0.f, 0.f, 0.f, 0.f};

  auto stage = [&](int sel, int k0) {
    u16* Ab = As + sel * (TM * 32);
    u16* Bb = Bs + sel * 4096;
#pragma unroll
    for (int j = 0; j < TM / 64; j++) {       // A: TM rows
      int rid = wv * (TM / 64) + j;
      int r = rid * 16 + srow;
      load_lds_16(A + (size_t)(m0 + r) * K + (k0 + scol), Ab + rid * 512);
    }
#pragma unroll
    for (int j = 0; j < 2; j++) {             // B: 128 rows
      int rid = wv * 2 + j;
      int r = rid * 16 + srow;
      load_lds_16(Bt + (size_t)(n0 + r) * K + (k0 + scol), Bb + rid * 512);
    }
  };

  const int NK = K >> 5;
  stage(0, 0);
  __syncthreads();
  for (int kt = 0; kt < NK; kt++) {
    const int cur = kt & 1;
    if (kt + 1 < NK) stage(cur ^ 1, (kt + 1) * 32);   // prefetch overlaps compute below
    const u16* Ab = As + cur * (TM * 32);
    const u16* Bb = Bs + cur * 4096;
    bf16x8 af[MI], bfr[4];
#pragma unroll
    for (int i = 0; i < MI; i++) af[i]  = *(const bf16x8*)&Ab[(wm + i * 16 + l16) * 32 + quad * 8];
#pragma unroll
    for (int j = 0; j < 4; j++)  bfr[j] = *(const bf16x8*)&Bb[(wn + j * 16 + l16) * 32 + quad * 8];
#pragma unroll
    for (int i = 0; i < MI; i++)
#pragma unroll
      for (int j = 0; j < 4; j++)
        acc[i][j] = __builtin_amdgcn_mfma_f32_16x16x32_bf16(af[i], bfr[j], acc[i][j], 0, 0, 0);
    __syncthreads();   // drains prefetch (after full compute overlap) + guards dbuf reuse
  }

  if (outH) {
    // 4 passes of 32 cols: deposit C-layout into cbuf[TM][36] (pad 36), sweep coalesced.
#pragma unroll
    for (int p = 0; p < 4; p++) {
      if (p) __syncthreads();
      if ((wv >> 1) == (p >> 1)) {
#pragma unroll
        for (int jj = 0; jj < 2; jj++) {
          int j = (p & 1) * 2 + jj;
          int gn = n0 + wn + j * 16 + l16;
          float bv = bias ? bias[gn] : 0.f;
          int lcol = jj * 16 + l16;
#pragma unroll
          for (int i = 0; i < MI; i++)
#pragma unroll
            for (int r = 0; r < 4; r++) {
              float v = acc[i][j][r] + bv;
              if (relu) v = fmaxf(v, 0.f);
              smem[(wm + i * 16 + quad * 4 + r) * 36 + lcol] = f2bf(v);
            }
        }
      }
      __syncthreads();
      const int gc0 = n0 + p * 32;
#pragma unroll
      for (int s = 0; s < TM / 32; s++) {
        int row = s * 32 + (tid >> 3);
        int seg = (tid & 7) * 4;
        u16 pk[4];
        *(uint2*)pk = *(const uint2*)&smem[row * 36 + seg];
        size_t o = (size_t)(m0 + row) * Nstore + gc0 + seg;
        if (resid) {
          u16 rv[4];
          *(uint2*)rv = *(const uint2*)&resid[o];
#pragma unroll
          for (int q2 = 0; q2 < 4; q2++) pk[q2] = f2bf(bf2f(pk[q2]) + bf2f(rv[q2]));
        }
        *(uint2*)&outH[o] = *(uint2*)pk;
      }
    }
  } else {
    // fp32 path (logits, N=65)
#pragma unroll
    for (int j = 0; j < 4; j++) {
      const int gn = n0 + wn + j * 16 + l16;
      if (gn < Nstore) {
        const float bv = bias ? bias[gn] : 0.f;
#pragma unroll
        for (int i = 0; i < MI; i++)
#pragma unroll
          for (int r = 0; r < 4; r++) {
            const int gm = m0 + wm + i * 16 + quad * 4 + r;
            outF[(size_t)gm * Nstore + gn] = acc[i][j][r] + bv;
          }
      }
    }
  }
}

// ---------------- fused causal attention ----------------
__global__ __launch_bounds__(512) void attn_k(const u16* __restrict__ qkv,
                                              u16* __restrict__ att) {
  __shared__ u16 Kc[64 * 64];
  __shared__ u16 Vtc[64 * 64];
  __shared__ u16 Pl[8 * 32 * 64];
  const int b = blockIdx.x / NH, h = blockIdx.x % NH;
  const int tid = threadIdx.x, lane = tid & 63, w = tid >> 6;
  const int quad = lane >> 4, l16 = lane & 15;
  const int rowb = b * T_SEQ;

  bf16x8 qf[2][2];
#pragma unroll
  for (int mi = 0; mi < 2; mi++)
#pragma unroll
    for (int kk = 0; kk < 2; kk++)
      qf[mi][kk] = *(const bf16x8*)(qkv + (size_t)(rowb + w * 32 + mi * 16 + l16) * QKV_N +
                                    h * 64 + kk * 32 + quad * 8);

  f32x4 Oa[2][4];
  float mrun[2][4], lrun[2][4];
#pragma unroll
  for (int mi = 0; mi < 2; mi++) {
#pragma unroll
    for (int di = 0; di < 4; di++) Oa[mi][di] = (f32x4){0.f, 0.f, 0.f, 0.f};
#pragma unroll
    for (int r = 0; r < 4; r++) { mrun[mi][r] = -1e30f; lrun[mi][r] = 0.f; }
  }

  u16* Pw = &Pl[w * 2048];
  const int nch = (w >> 1) + 1;
  const int sr = tid >> 3, sseg = (tid & 7) * 8;

  for (int c = 0; c < 4; c++) {
    const int s0 = c * 64;
    __syncthreads();
    *(uint4*)&Kc[sr * 64 + sseg] =
        *(const uint4*)(qkv + (size_t)(rowb + s0 + sr) * QKV_N + 384 + h * 64 + sseg);
    {
      union { uint4 u; u16 us[8]; } tb;
      tb.u = *(const uint4*)(qkv + (size_t)(rowb + s0 + sr) * QKV_N + 768 + h * 64 + sseg);
#pragma unroll
      for (int j = 0; j < 8; j++) Vtc[(sseg + j) * 64 + sr] = tb.us[j];
    }
    __syncthreads();
    if (c >= nch) continue;

    f32x4 S[2][4];
    bf16x8 kf[4][2];
#pragma unroll
    for (int ni = 0; ni < 4; ni++)
#pragma unroll
      for (int kk = 0; kk < 2; kk++)
        kf[ni][kk] = *(const bf16x8*)&Kc[(ni * 16 + l16) * 64 + kk * 32 + quad * 8];
#pragma unroll
    for (int mi = 0; mi < 2; mi++)
#pragma unroll
      for (int ni = 0; ni < 4; ni++) {
        f32x4 z = (f32x4){0.f, 0.f, 0.f, 0.f};
        z = __builtin_amdgcn_mfma_f32_16x16x32_bf16(qf[mi][0], kf[ni][0], z, 0, 0, 0);
        S[mi][ni] = __builtin_amdgcn_mfma_f32_16x16x32_bf16(qf[mi][1], kf[ni][1], z, 0, 0, 0);
      }
    const bool diag = (c == nch - 1);
#pragma unroll
    for (int mi = 0; mi < 2; mi++)
#pragma unroll
      for (int ni = 0; ni < 4; ni++)
#pragma unroll
        for (int r = 0; r < 4; r++) {
          float xv = S[mi][ni][r] * 0.125f;
          if (diag) {
            int t = w * 32 + mi * 16 + quad * 4 + r;
            int s = s0 + ni * 16 + l16;
            if (s > t) xv = -1e30f;
          }
          S[mi][ni][r] = xv;
        }
#pragma unroll
    for (int mi = 0; mi < 2; mi++)
#pragma unroll
      for (int r = 0; r < 4; r++) {
        float mx = fmaxf(fmaxf(S[mi][0][r], S[mi][1][r]), fmaxf(S[mi][2][r], S[mi][3][r]));
        mx = fmaxf(mx, __shfl_xor(mx, 1));
        mx = fmaxf(mx, __shfl_xor(mx, 2));
        mx = fmaxf(mx, __shfl_xor(mx, 4));
        mx = fmaxf(mx, __shfl_xor(mx, 8));
        float mnew = fmaxf(mrun[mi][r], mx);
        float alpha = __expf(mrun[mi][r] - mnew);
        float ls = 0.f;
#pragma unroll
        for (int ni = 0; ni < 4; ni++) {
          float p = __expf(S[mi][ni][r] - mnew);
          S[mi][ni][r] = p; ls += p;
        }
        ls += __shfl_xor(ls, 1); ls += __shfl_xor(ls, 2);
        ls += __shfl_xor(ls, 4); ls += __shfl_xor(ls, 8);
        lrun[mi][r] = lrun[mi][r] * alpha + ls;
        mrun[mi][r] = mnew;
#pragma unroll
        for (int di = 0; di < 4; di++) Oa[mi][di][r] *= alpha;
      }
#pragma unroll
    for (int mi = 0; mi < 2; mi++)
#pragma unroll
      for (int ni = 0; ni < 4; ni++)
#pragma unroll
        for (int r = 0; r < 4; r++)
          Pw[(mi * 16 + quad * 4 + r) * 64 + ni * 16 + l16] = f2bf(S[mi][ni][r]);
    bf16x8 pf[2][2], vf[4][2];
#pragma unroll
    for (int mi = 0; mi < 2; mi++)
#pragma unroll
      for (int kk = 0; kk < 2; kk++)
        pf[mi][kk] = *(const bf16x8*)&Pw[(mi * 16 + l16) * 64 + kk * 32 + quad * 8];
#pragma unroll
    for (int di = 0; di < 4; di++)
#pragma unroll
      for (int kk = 0; kk < 2; kk++)
        vf[di][kk] = *(const bf16x8*)&Vtc[(di * 16 + l16) * 64 + kk * 32 + quad * 8];
#pragma unroll
    for (int mi = 0; mi < 2; mi++)
#pragma unroll
      for (int di = 0; di < 4; di++) {
        Oa[mi][di] = __builtin_amdgcn_mfma_f32_16x16x32_bf16(pf[mi][0], vf[di][0], Oa[mi][di], 0, 0, 0);
        Oa[mi][di] = __builtin_amdgcn_mfma_f32_16x16x32_bf16(pf[mi][1], vf[di][1], Oa[mi][di], 0, 0, 0);
      }
  }

#pragma unroll
  for (int mi = 0; mi < 2; mi++)
#pragma unroll
    for (int r = 0; r < 4; r++) {
      float inv = 1.f / lrun[mi][r];
      int t = w * 32 + mi * 16 + quad * 4 + r;
#pragma unroll
      for (int di = 0; di < 4; di++)
        att[(size_t)(rowb + t) * E_DIM + h * 64 + di * 16 + l16] = f2bf(Oa[mi][di][r] * inv);
    }
}

// ---------------- loss: grid-stride, 1 atomic per block ----------------
__global__ __launch_bounds__(256) void loss_k(const float* __restrict__ logits,
                                              const int* __restrict__ tgt,
                                              float* __restrict__ loss) {
  __shared__ float part[4];
  const int tid = threadIdx.x, lane = tid & 63, w = tid >> 6;
  const int wave_id = blockIdx.x * 4 + w;          // 512 blocks -> 2048 waves
  float acc = 0.f;
  for (int t = wave_id; t < BT; t += 2048) {
    const float* row = logits + (size_t)t * VOC;
    float a = row[lane];
    float b = (lane == 0) ? row[64] : -1e30f;
    float mx = fmaxf(a, b);
#pragma unroll
    for (int d = 1; d < 64; d <<= 1) mx = fmaxf(mx, __shfl_xor(mx, d));
    float sum = __expf(a - mx) + ((lane == 0) ? __expf(b - mx) : 0.f);
#pragma unroll
    for (int d = 1; d < 64; d <<= 1) sum += __shfl_xor(sum, d);
    if (lane == 0) acc += mx + __logf(sum) - row[tgt[t]];
  }
  if (lane == 0) part[w] = acc;
  __syncthreads();
  if (tid == 0)
    atomicAdd(loss, (part[0] + part[1] + part[2] + part[3]) * (1.f / (float)BT));
}

// ---------------- host ----------------
extern "C" void kernel_launch(void* const* d_in, const int* in_sizes, int n_in,
                              void* d_out, int out_size, void* d_ws, size_t ws_size,
                              hipStream_t stream) {
  (void)in_sizes; (void)n_in; (void)out_size; (void)ws_size;
  const int*   idx  = (const int*)d_in[0];
  const int*   tgt  = (const int*)d_in[1];
  const float* tok  = (const float*)d_in[2];
  const float* pos  = (const float*)d_in[3];
  const float* Wq   = (const float*)d_in[4];
  const float* Wk   = (const float*)d_in[5];
  const float* Wv   = (const float*)d_in[6];
  const float* Wo   = (const float*)d_in[7];
  const float* bo   = (const float*)d_in[8];
  const float* ln1s = (const float*)d_in[9];
  const float* ln1b = (const float*)d_in[10];
  const float* ln2s = (const float*)d_in[11];
  const float* ln2b = (const float*)d_in[12];
  const float* W1   = (const float*)d_in[13];
  const float* b1   = (const float*)d_in[14];
  const float* W2   = (const float*)d_in[15];
  const float* b2   = (const float*)d_in[16];
  const float* lnfs = (const float*)d_in[17];
  const float* lnfb = (const float*)d_in[18];
  const float* Wout = (const float*)d_in[19];
  const float* bout = (const float*)d_in[20];

  char* w = (char*)d_ws;
  u16* x      = (u16*)w;    w += (size_t)BT * E_DIM * 2;      // bf16 residual stream
  u16* hb     = (u16*)w;    w += (size_t)BT * E_DIM * 2;
  u16* attb   = (u16*)w;    w += (size_t)BT * E_DIM * 2;
  u16* big    = (u16*)w;    w += (size_t)BT * FF_DIM * 2;     // qkv / ff union
  u16* Wqkv_t = (u16*)w;    w += (size_t)NL * QKV_N * E_DIM * 2;
  u16* Wo_t   = (u16*)w;    w += (size_t)NL * E_DIM * E_DIM * 2;
  u16* W1_t   = (u16*)w;    w += (size_t)NL * FF_DIM * E_DIM * 2;
  u16* W2_t   = (u16*)w;    w += (size_t)NL * E_DIM * FF_DIM * 2;
  u16* Wout_t = (u16*)w;    w += (size_t)128 * E_DIM * 2;
  u16* qkv = big;
  u16* ff  = big;

  float* logits = (float*)d_out;
  float* loss   = logits + (size_t)BT * VOC;

  hipMemsetAsync(Wout_t, 0, 128 * E_DIM * 2, stream);
  transpose_t<<<dim3(12, 2, 36), 256, 0, stream>>>(Wq, Wqkv_t, 384, 64,
      24576, 442368, 6, 24576, 0);
  transpose_t<<<dim3(12, 2, 36), 256, 0, stream>>>(Wk, Wqkv_t, 384, 64,
      24576, 442368, 6, 24576, (long)384 * 384);
  transpose_t<<<dim3(12, 2, 36), 256, 0, stream>>>(Wv, Wqkv_t, 384, 64,
      24576, 442368, 6, 24576, (long)768 * 384);
  transpose_t<<<dim3(12, 12, 6), 256, 0, stream>>>(Wo, Wo_t, 384, 384,
      147456, 147456, 1, 0, 0);
  transpose_t<<<dim3(12, 48, 6), 256, 0, stream>>>(W1, W1_t, 384, 1536,
      589824, 589824, 1, 0, 0);
  transpose_t<<<dim3(48, 12, 6), 256, 0, stream>>>(W2, W2_t, 1536, 384,
      589824, 589824, 1, 0, 0);
  transpose_t<<<dim3(12, 3, 1), 256, 0, stream>>>(Wout, Wout_t, 384, 65,
      0, 0, 1, 0, 0);

  embed_k<<<6144, 256, 0, stream>>>(idx, tok, pos, x);

  for (int l = 0; l < NL; l++) {
    ln_k<<<8192, 256, 0, stream>>>(x, ln1s + l * E_DIM, ln1b + l * E_DIM, hb);
    gemm_bt<256><<<dim3(128, 9), 256, 0, stream>>>(hb, Wqkv_t + (size_t)l * QKV_N * E_DIM,
                                                   384, QKV_N, nullptr, nullptr, qkv, nullptr, 0);
    attn_k<<<768, 512, 0, stream>>>(qkv, attb);
    gemm_bt<128><<<dim3(256, 3), 256, 0, stream>>>(attb, Wo_t + (size_t)l * E_DIM * E_DIM,
                                                   384, E_DIM, bo + l * E_DIM, x, x, nullptr, 0);
    ln_k<<<8192, 256, 0, stream>>>(x, ln2s + l * E_DIM, ln2b + l * E_DIM, hb);
    gemm_bt<256><<<dim3(128, 12), 256, 0, stream>>>(hb, W1_t + (size_t)l * FF_DIM * E_DIM,
                                                    384, FF_DIM, b1 + l * FF_DIM, nullptr, ff, nullptr, 1);
    gemm_bt<128><<<dim3(256, 3), 256, 0, stream>>>(ff, W2_t + (size_t)l * E_DIM * FF_DIM,
                                                   1536, E_DIM, b2 + l * E_DIM, x, x, nullptr, 0);
  }
  ln_k<<<8192, 256, 0, stream>>>(x, lnfs, lnfb, hb);
  gemm_bt<128><<<dim3(256, 1), 256, 0, stream>>>(hb, Wout_t, 384, VOC, bout, nullptr, nullptr, logits, 0);

  hipMemsetAsync(loss, 0, 4, stream);
  loss_k<<<512, 256, 0, stream>>>(logits, tgt, loss);
}